// Round 1
// baseline (494.077 us; speedup 1.0000x reference)
//
#include <hip/hip_runtime.h>
#include <math.h>

// Problem constants
#define BB 4
#define CC 64
#define HH 64
#define WW 64
#define HWP 4096            // H*W
#define NPTS 4096           // sample points per batch
#define NSPLIT 2            // n-splits in flash attention
constexpr float K_EPS   = 1e-5f;
constexpr float K_SCALE = 0.125f;    // C^-0.5
constexpr float K_OFR   = 4.0f;

// Workspace layout (float offsets)
//  Q     : [B][C][HW]            1,048,576
//  GXY   : [B][HW][2]               32,768
//  K     : [B][C][N]             1,048,576
//  V     : [B][C][N]             1,048,576
//  OPART : [NS][B][M][C]         2,097,152
//  DPART : [NS][B][M]               32,768
#define Q_OFF   0
#define GXY_OFF 1048576
#define K_OFF   1081344
#define V_OFF   2129920
#define OP_OFF  3178496
#define DP_OFF  5275648
// total = 5,308,416 floats = 21.2 MB

// ---------------------------------------------------------------------------
// Kernel 1: q = conv1x1(prompt, wq, bq).  One thread per pixel, all 64 outs.
// ---------------------------------------------------------------------------
__global__ __launch_bounds__(256) void k_qproj(
    const float* __restrict__ prompt, const float* __restrict__ wq,
    const float* __restrict__ bq, float* __restrict__ q) {
  __shared__ float w_s[CC * CC];
  int tid = threadIdx.x;
  for (int i = tid; i < CC * CC; i += 256) w_s[i] = wq[i];
  __syncthreads();
  int pix = blockIdx.x * 256 + tid;   // [0, B*HW)
  int b = pix >> 12;
  int hw = pix & 4095;
  float p[CC];
#pragma unroll
  for (int c = 0; c < CC; ++c) p[c] = prompt[(b * CC + c) * HWP + hw];
  for (int o = 0; o < CC; ++o) {
    float acc = bq[o];
#pragma unroll
    for (int c = 0; c < CC; ++c) acc = fmaf(w_s[o * CC + c], p[c], acc);
    q[(b * CC + o) * HWP + hw] = acc;
  }
}

// ---------------------------------------------------------------------------
// Kernel 2: depthwise3x3(q) + bias -> LN(channel) -> GELU(exact)
//           -> offset proj (2xC) -> tanh -> sample coords gx,gy.
// Block = one row (64 px) x 4 channel-groups of 16.  Grid = B*H = 256.
// ---------------------------------------------------------------------------
__global__ __launch_bounds__(256) void k_offsets(
    const float* __restrict__ q, const float* __restrict__ dw_w,
    const float* __restrict__ dw_b, const float* __restrict__ ln_w,
    const float* __restrict__ ln_b, const float* __restrict__ off_w,
    float* __restrict__ gxy) {
  int tid = threadIdx.x;
  int x = tid & 63;
  int cg = tid >> 6;                // 0..3
  int by = blockIdx.x;              // b*H + y
  int b = by >> 6;
  int y = by & 63;

  __shared__ float red0[4][64];
  __shared__ float red1[4][64];

  float t[16];
#pragma unroll
  for (int i = 0; i < 16; ++i) {
    int c = cg * 16 + i;
    float acc = dw_b[c];
    const float* qc = q + (b * CC + c) * HWP;
#pragma unroll
    for (int ky = 0; ky < 3; ++ky) {
      int yy = y + ky - 1;
      bool yok = (yy >= 0) && (yy < HH);
#pragma unroll
      for (int kx = 0; kx < 3; ++kx) {
        int xx = x + kx - 1;
        bool ok = yok && (xx >= 0) && (xx < WW);
        float v = ok ? qc[yy * WW + xx] : 0.f;
        acc = fmaf(dw_w[c * 9 + ky * 3 + kx], v, acc);
      }
    }
    t[i] = acc;
  }
  float s1 = 0.f, s2 = 0.f;
#pragma unroll
  for (int i = 0; i < 16; ++i) { s1 += t[i]; s2 += t[i] * t[i]; }
  red0[cg][x] = s1;
  red1[cg][x] = s2;
  __syncthreads();
  float mu = (red0[0][x] + red0[1][x] + red0[2][x] + red0[3][x]) * (1.f / 64.f);
  float ms = (red1[0][x] + red1[1][x] + red1[2][x] + red1[3][x]) * (1.f / 64.f);
  float rstd = rsqrtf(ms - mu * mu + K_EPS);

  float oy = 0.f, ox = 0.f;
#pragma unroll
  for (int i = 0; i < 16; ++i) {
    int c = cg * 16 + i;
    float g = (t[i] - mu) * rstd * ln_w[c] + ln_b[c];
    g = 0.5f * g * (1.f + erff(g * 0.70710678118654752f));  // exact GELU
    oy = fmaf(off_w[c], g, oy);          // off_w[0][c] -> y offset
    ox = fmaf(off_w[CC + c], g, ox);     // off_w[1][c] -> x offset
  }
  __syncthreads();   // red arrays reused
  red0[cg][x] = oy;
  red1[cg][x] = ox;
  __syncthreads();
  if (cg == 0) {
    float osy = red0[0][x] + red0[1][x] + red0[2][x] + red0[3][x];
    float osx = red1[0][x] + red1[1][x] + red1[2][x] + red1[3][x];
    osy = tanhf(osy) * (K_OFR / (HH - 1));
    osx = tanhf(osx) * (K_OFR / (WW - 1));
    float ry = (y + 0.5f) * (2.f / 63.f) - 1.f;
    float rx = (x + 0.5f) * (2.f / 63.f) - 1.f;
    float py = osy + ry;
    float px = osx + rx;
    float gx = (px + 1.f) * 0.5f * (WW - 1);
    float gy = (py + 1.f) * 0.5f * (HH - 1);
    int n = y * WW + x;
    gxy[(b * HWP + n) * 2 + 0] = gx;
    gxy[(b * HWP + n) * 2 + 1] = gy;
  }
}

// ---------------------------------------------------------------------------
// Kernel 3: bilinear sample kv at (gx,gy) (zero-pad OOB) -> xs[64]
//           -> k = wk@xs + bk, v = wv@xs + bv.  One thread per point.
// ---------------------------------------------------------------------------
__global__ __launch_bounds__(256) void k_sample_kv(
    const float* __restrict__ kv, const float* __restrict__ gxy,
    const float* __restrict__ wk, const float* __restrict__ bk,
    const float* __restrict__ wv, const float* __restrict__ bv,
    float* __restrict__ kq, float* __restrict__ vq) {
  __shared__ float wk_s[CC * CC];
  __shared__ float wv_s[CC * CC];
  int tid = threadIdx.x;
  for (int i = tid; i < CC * CC; i += 256) { wk_s[i] = wk[i]; wv_s[i] = wv[i]; }
  __syncthreads();

  int p = blockIdx.x * 256 + tid;   // b*HW + n
  int b = p >> 12;
  int n = p & 4095;
  float gx = gxy[p * 2 + 0];
  float gy = gxy[p * 2 + 1];
  float x0f = floorf(gx), y0f = floorf(gy);
  float wx = gx - x0f, wy = gy - y0f;
  int x0 = (int)x0f, y0 = (int)y0f;
  int x1 = x0 + 1, y1 = y0 + 1;
  float m00 = (x0 >= 0 && x0 < WW && y0 >= 0 && y0 < HH) ? 1.f : 0.f;
  float m01 = (x1 >= 0 && x1 < WW && y0 >= 0 && y0 < HH) ? 1.f : 0.f;
  float m10 = (x0 >= 0 && x0 < WW && y1 >= 0 && y1 < HH) ? 1.f : 0.f;
  float m11 = (x1 >= 0 && x1 < WW && y1 >= 0 && y1 < HH) ? 1.f : 0.f;
  int x0c = min(max(x0, 0), WW - 1), x1c = min(max(x1, 0), WW - 1);
  int y0c = min(max(y0, 0), HH - 1), y1c = min(max(y1, 0), HH - 1);
  int i00 = y0c * WW + x0c, i01 = y0c * WW + x1c;
  int i10 = y1c * WW + x0c, i11 = y1c * WW + x1c;
  float w00 = m00 * (1.f - wx) * (1.f - wy);
  float w01 = m01 * wx * (1.f - wy);
  float w10 = m10 * (1.f - wx) * wy;
  float w11 = m11 * wx * wy;

  const float* base = kv + b * CC * HWP;
  float xs[CC];
#pragma unroll
  for (int c = 0; c < CC; ++c) {
    const float* pc = base + c * HWP;
    xs[c] = w00 * pc[i00] + w01 * pc[i01] + w10 * pc[i10] + w11 * pc[i11];
  }
  for (int o = 0; o < CC; ++o) {
    float ak = bk[o], av = bv[o];
#pragma unroll
    for (int c = 0; c < CC; ++c) {
      ak = fmaf(wk_s[o * CC + c], xs[c], ak);
      av = fmaf(wv_s[o * CC + c], xs[c], av);
    }
    kq[(b * CC + o) * NPTS + n] = ak;
    vq[(b * CC + o) * NPTS + n] = av;
  }
}

// ---------------------------------------------------------------------------
// Kernel 4: flash attention partials.  Grid = B * NSPLIT * 64 m-tiles = 512.
// Block 256 thr = 16(tm) x 16(tn); per-thread 4x4 register tiles.
// Logits tiny (|s|<~0.2) -> single-pass exp, no max subtraction.
// ---------------------------------------------------------------------------
__global__ __launch_bounds__(256) void k_attn(
    const float* __restrict__ q, const float* __restrict__ kq,
    const float* __restrict__ vq, float* __restrict__ opart,
    float* __restrict__ dpart) {
  int tid = threadIdx.x;
  int tm = tid & 15, tn = tid >> 4;
  int blk = blockIdx.x;             // (b*NS + ns)*64 + mt
  int mt = blk & 63;
  int bns = blk >> 6;
  int ns = bns & 1;
  int b = bns >> 1;
  int m0 = mt * 64;

  __shared__ float q_s[64 * 64];    // [c][m]
  __shared__ float k_s[64 * 64];    // [c][n]
  __shared__ float v_s[64 * 68];    // [n][c], pad 4 to kill write conflicts
  __shared__ float p_s[64 * 64];    // [n][m]

  const float* qb = q + b * CC * HWP;
  const float* kb = kq + b * CC * NPTS;
  const float* vb = vq + b * CC * NPTS;

#pragma unroll
  for (int it = 0; it < 16; ++it) {
    int idx = it * 256 + tid;
    int c = idx >> 6, m = idx & 63;
    q_s[c * 64 + m] = qb[c * HWP + m0 + m];
  }

  float o_acc[4][4];
  float d_acc[4];
#pragma unroll
  for (int i = 0; i < 4; ++i) {
    d_acc[i] = 0.f;
#pragma unroll
    for (int j = 0; j < 4; ++j) o_acc[i][j] = 0.f;
  }

  int nstart = ns * (NPTS / NSPLIT);
  for (int nt = 0; nt < (NPTS / NSPLIT) / 64; ++nt) {
    int n0 = nstart + nt * 64;
    __syncthreads();
#pragma unroll
    for (int it = 0; it < 16; ++it) {
      int idx = it * 256 + tid;
      int c = idx >> 6, n = idx & 63;
      float kvv = kb[c * NPTS + n0 + n];
      float vvv = vb[c * NPTS + n0 + n];
      k_s[c * 64 + n] = kvv;
      v_s[n * 68 + c] = vvv;
    }
    __syncthreads();

    // GEMM1: S[4m][4n] = sum_c q_s[c][m] * k_s[c][n]
    float s[4][4];
#pragma unroll
    for (int i = 0; i < 4; ++i)
#pragma unroll
      for (int j = 0; j < 4; ++j) s[i][j] = 0.f;
    for (int c = 0; c < 64; ++c) {
      float4 a = *(const float4*)&q_s[c * 64 + tm * 4];
      float4 kk = *(const float4*)&k_s[c * 64 + tn * 4];
      float av[4] = {a.x, a.y, a.z, a.w};
      float kv4[4] = {kk.x, kk.y, kk.z, kk.w};
#pragma unroll
      for (int i = 0; i < 4; ++i)
#pragma unroll
        for (int j = 0; j < 4; ++j) s[i][j] = fmaf(av[i], kv4[j], s[i][j]);
    }
    // exp + write P (p_s[n][m]) + denominator partials
#pragma unroll
    for (int j = 0; j < 4; ++j) {
      float4 pj;
      pj.x = __expf(s[0][j] * K_SCALE);
      pj.y = __expf(s[1][j] * K_SCALE);
      pj.z = __expf(s[2][j] * K_SCALE);
      pj.w = __expf(s[3][j] * K_SCALE);
      *(float4*)&p_s[(tn * 4 + j) * 64 + tm * 4] = pj;
      d_acc[0] += pj.x; d_acc[1] += pj.y; d_acc[2] += pj.z; d_acc[3] += pj.w;
    }
    __syncthreads();
    // GEMM2: O[4m][4c] += sum_n p_s[n][m] * v_s[n][c]
    for (int n = 0; n < 64; ++n) {
      float4 pp = *(const float4*)&p_s[n * 64 + tm * 4];
      float4 vv = *(const float4*)&v_s[n * 68 + tn * 4];
      float pa[4] = {pp.x, pp.y, pp.z, pp.w};
      float va[4] = {vv.x, vv.y, vv.z, vv.w};
#pragma unroll
      for (int i = 0; i < 4; ++i)
#pragma unroll
        for (int j = 0; j < 4; ++j) o_acc[i][j] = fmaf(pa[i], va[j], o_acc[i][j]);
    }
  }

  // write O partials: opart[ns][b][m][c]
  float* op = opart + (size_t)(ns * BB + b) * HWP * CC;
#pragma unroll
  for (int i = 0; i < 4; ++i) {
    float4 o4;
    o4.x = o_acc[i][0]; o4.y = o_acc[i][1]; o4.z = o_acc[i][2]; o4.w = o_acc[i][3];
    *(float4*)&op[(size_t)(m0 + tm * 4 + i) * CC + tn * 4] = o4;
  }
  // reduce denominator over tn (16 columns) via k_s scratch
  __syncthreads();
  {
    float4 d4;
    d4.x = d_acc[0]; d4.y = d_acc[1]; d4.z = d_acc[2]; d4.w = d_acc[3];
    *(float4*)&k_s[tn * 64 + tm * 4] = d4;
  }
  __syncthreads();
  if (tid < 64) {
    float d = 0.f;
#pragma unroll
    for (int t = 0; t < 16; ++t) d += k_s[t * 64 + tid];
    dpart[(ns * BB + b) * HWP + m0 + tid] = d;
  }
}

// ---------------------------------------------------------------------------
// Kernel 5: combine partials, normalize, project with wo, write d_out.
// Grid = B * 64 m-tiles = 256 blocks.
// ---------------------------------------------------------------------------
__global__ __launch_bounds__(256) void k_out(
    const float* __restrict__ opart, const float* __restrict__ dpart,
    const float* __restrict__ wo, const float* __restrict__ bo,
    float* __restrict__ out) {
  __shared__ float wo_s[CC * CC];
  __shared__ float t_s[64 * 65];    // [m][c] padded
  int tid = threadIdx.x;
  int blk = blockIdx.x;             // b*64 + mt
  int b = blk >> 6, mt = blk & 63, m0 = mt * 64;
  for (int i = tid; i < CC * CC; i += 256) wo_s[i] = wo[i];

  const float* o0 = opart + (size_t)(0 * BB + b) * HWP * CC;
  const float* o1 = opart + (size_t)(1 * BB + b) * HWP * CC;
  const float* d0 = dpart + (0 * BB + b) * HWP;
  const float* d1 = dpart + (1 * BB + b) * HWP;
#pragma unroll
  for (int it = 0; it < 16; ++it) {
    int idx = it * 256 + tid;
    int m = idx >> 6, c = idx & 63;
    float denom = d0[m0 + m] + d1[m0 + m];
    float val = (o0[(size_t)(m0 + m) * CC + c] + o1[(size_t)(m0 + m) * CC + c]) / denom;
    t_s[m * 65 + c] = val;
  }
  __syncthreads();
  int ml = tid & 63, og = tid >> 6;
  for (int oo = 0; oo < 16; ++oo) {
    int o = og * 16 + oo;
    float acc = bo[o];
#pragma unroll
    for (int c = 0; c < 64; ++c) acc = fmaf(wo_s[o * CC + c], t_s[ml * 65 + c], acc);
    out[(size_t)(b * CC + o) * HWP + m0 + ml] = acc;
  }
}

// ---------------------------------------------------------------------------
extern "C" void kernel_launch(void* const* d_in, const int* in_sizes, int n_in,
                              void* d_out, int out_size, void* d_ws, size_t ws_size,
                              hipStream_t stream) {
  const float* prompt = (const float*)d_in[0];
  const float* kv     = (const float*)d_in[1];
  const float* wq     = (const float*)d_in[2];
  const float* bq     = (const float*)d_in[3];
  const float* wk     = (const float*)d_in[4];
  const float* bk     = (const float*)d_in[5];
  const float* wv     = (const float*)d_in[6];
  const float* bv     = (const float*)d_in[7];
  const float* wo     = (const float*)d_in[8];
  const float* bo     = (const float*)d_in[9];
  const float* dw_w   = (const float*)d_in[10];
  const float* dw_b   = (const float*)d_in[11];
  const float* ln_w   = (const float*)d_in[12];
  const float* ln_b   = (const float*)d_in[13];
  const float* off_w  = (const float*)d_in[14];
  float* out = (float*)d_out;
  float* ws  = (float*)d_ws;

  float* q     = ws + Q_OFF;
  float* gxy   = ws + GXY_OFF;
  float* kq    = ws + K_OFF;
  float* vq    = ws + V_OFF;
  float* opart = ws + OP_OFF;
  float* dpart = ws + DP_OFF;

  hipLaunchKernelGGL(k_qproj, dim3(BB * HWP / 256), dim3(256), 0, stream,
                     prompt, wq, bq, q);
  hipLaunchKernelGGL(k_offsets, dim3(BB * HH), dim3(256), 0, stream,
                     q, dw_w, dw_b, ln_w, ln_b, off_w, gxy);
  hipLaunchKernelGGL(k_sample_kv, dim3(BB * NPTS / 256), dim3(256), 0, stream,
                     kv, gxy, wk, bk, wv, bv, kq, vq);
  hipLaunchKernelGGL(k_attn, dim3(BB * NSPLIT * 64), dim3(256), 0, stream,
                     q, kq, vq, opart, dpart);
  hipLaunchKernelGGL(k_out, dim3(BB * 64), dim3(256), 0, stream,
                     opart, dpart, wo, bo, out);
}

// Round 3
// 182.500 us; speedup vs baseline: 2.7073x; 2.7073x over previous
//
#include <hip/hip_runtime.h>
#include <math.h>

// Problem constants
#define BB 4
#define CC 64
#define HH 64
#define WW 64
#define HWP 4096            // H*W
#define NPTS 4096           // sample points per batch
#define NSPLIT 2            // n-splits in flash attention
#define LDP 72              // padded LDS row stride (bf16 elems): +8 -> 2-way (free)
constexpr float K_EPS   = 1e-5f;
constexpr float K_SCALE = 0.125f;    // C^-0.5
constexpr float K_OFR   = 4.0f;

// Workspace layout (float offsets)
#define QF_OFF  0            // fp32 q [B][C][HW]           1,048,576 fl
#define QB_OFF  1048576      // bf16 q [B][M][C]              524,288 fl
#define GXY_OFF 1572864      // [B][HW][2]                     32,768 fl
#define KB_OFF  1605632      // bf16 k [B][N][C]              524,288 fl
#define VB_OFF  2129920      // bf16 v [B][C][N]              524,288 fl
#define OP_OFF  2654208      // fp32 opart [NS][B][M][C]    2,097,152 fl
#define DP_OFF  4751360      // fp32 dpart [NS][B][M]          32,768 fl
// total = 4,784,128 floats = 19.1 MB (< proven 21.2 MB)

typedef short frag8 __attribute__((ext_vector_type(8)));   // 8 bf16 (4 VGPRs)
typedef float f32x4 __attribute__((ext_vector_type(4)));

static __device__ inline unsigned short f2bf(float f) {
  unsigned int u = __builtin_bit_cast(unsigned int, f);
  unsigned int r = (u + 0x7fffu + ((u >> 16) & 1u)) >> 16;
  return (unsigned short)r;
}

// ---------------------------------------------------------------------------
// Kernel 1: q = conv1x1(prompt, wq, bq); writes fp32 [B][C][HW] (for k_offsets)
// and bf16 [B][M][C] (for MFMA attention A-fragments).
// Grid 256 blocks; block = 64 pixels x 4 o-groups of 16.
// ---------------------------------------------------------------------------
__global__ __launch_bounds__(256) void k_qproj(
    const float* __restrict__ prompt, const float* __restrict__ wq,
    const float* __restrict__ bq, float* __restrict__ qf,
    unsigned short* __restrict__ qb) {
  __shared__ float w_s[64 * 64];
  __shared__ float p_s[64 * 64];           // [c][pix]
  __shared__ unsigned short t_s[64 * 68];  // [pix][c] pad 4
  int tid = threadIdx.x;
  int blk = blockIdx.x;                    // b*64 + tile
  int b = blk >> 6; int hw0 = (blk & 63) * 64;
#pragma unroll
  for (int i = 0; i < 16; ++i) w_s[i * 256 + tid] = wq[i * 256 + tid];
#pragma unroll
  for (int i = 0; i < 16; ++i) {
    int idx = i * 256 + tid; int c = idx >> 6, pix = idx & 63;
    p_s[idx] = prompt[(size_t)(b * CC + c) * HWP + hw0 + pix];
  }
  __syncthreads();
  int x = tid & 63, og = tid >> 6;
  float acc[16];
#pragma unroll
  for (int oo = 0; oo < 16; ++oo) acc[oo] = bq[og * 16 + oo];
  for (int cg = 0; cg < 16; ++cg) {
    float p0 = p_s[(cg * 4 + 0) * 64 + x];
    float p1 = p_s[(cg * 4 + 1) * 64 + x];
    float p2 = p_s[(cg * 4 + 2) * 64 + x];
    float p3 = p_s[(cg * 4 + 3) * 64 + x];
#pragma unroll
    for (int oo = 0; oo < 16; ++oo) {
      const float4 w4 = *(const float4*)&w_s[(og * 16 + oo) * 64 + cg * 4];
      acc[oo] = fmaf(w4.x, p0, fmaf(w4.y, p1, fmaf(w4.z, p2, fmaf(w4.w, p3, acc[oo]))));
    }
  }
#pragma unroll
  for (int oo = 0; oo < 16; ++oo) {
    int o = og * 16 + oo;
    qf[(size_t)(b * CC + o) * HWP + hw0 + x] = acc[oo];
    t_s[x * 68 + o] = f2bf(acc[oo]);
  }
  __syncthreads();
#pragma unroll
  for (int i = 0; i < 4; ++i) {
    int idx = i * 256 + tid;               // 1024 ushort4 chunks
    int pix = idx >> 4, c4 = idx & 15;
    ushort4 v = *(const ushort4*)&t_s[pix * 68 + c4 * 4];
    *(ushort4*)&qb[(size_t)(b * HWP + hw0 + pix) * CC + c4 * 4] = v;
  }
}

// ---------------------------------------------------------------------------
// Kernel 2: depthwise3x3(q) + bias -> LN(channel) -> GELU(exact)
//           -> offset proj (2xC) -> tanh -> sample coords gx,gy.
// Block = one row (64 px) x 4 channel-groups of 16.  Grid = B*H = 256.
// ---------------------------------------------------------------------------
__global__ __launch_bounds__(256) void k_offsets(
    const float* __restrict__ q, const float* __restrict__ dw_w,
    const float* __restrict__ dw_b, const float* __restrict__ ln_w,
    const float* __restrict__ ln_b, const float* __restrict__ off_w,
    float* __restrict__ gxy) {
  int tid = threadIdx.x;
  int x = tid & 63;
  int cg = tid >> 6;                // 0..3
  int by = blockIdx.x;              // b*H + y
  int b = by >> 6;
  int y = by & 63;

  __shared__ float red0[4][64];
  __shared__ float red1[4][64];

  float t[16];
#pragma unroll
  for (int i = 0; i < 16; ++i) {
    int c = cg * 16 + i;
    float acc = dw_b[c];
    const float* qc = q + (size_t)(b * CC + c) * HWP;
#pragma unroll
    for (int ky = 0; ky < 3; ++ky) {
      int yy = y + ky - 1;
      bool yok = (yy >= 0) && (yy < HH);
#pragma unroll
      for (int kx = 0; kx < 3; ++kx) {
        int xx = x + kx - 1;
        bool ok = yok && (xx >= 0) && (xx < WW);
        float v = ok ? qc[yy * WW + xx] : 0.f;
        acc = fmaf(dw_w[c * 9 + ky * 3 + kx], v, acc);
      }
    }
    t[i] = acc;
  }
  float s1 = 0.f, s2 = 0.f;
#pragma unroll
  for (int i = 0; i < 16; ++i) { s1 += t[i]; s2 += t[i] * t[i]; }
  red0[cg][x] = s1;
  red1[cg][x] = s2;
  __syncthreads();
  float mu = (red0[0][x] + red0[1][x] + red0[2][x] + red0[3][x]) * (1.f / 64.f);
  float ms = (red1[0][x] + red1[1][x] + red1[2][x] + red1[3][x]) * (1.f / 64.f);
  float rstd = rsqrtf(ms - mu * mu + K_EPS);

  float oy = 0.f, ox = 0.f;
#pragma unroll
  for (int i = 0; i < 16; ++i) {
    int c = cg * 16 + i;
    float g = (t[i] - mu) * rstd * ln_w[c] + ln_b[c];
    g = 0.5f * g * (1.f + erff(g * 0.70710678118654752f));  // exact GELU
    oy = fmaf(off_w[c], g, oy);
    ox = fmaf(off_w[CC + c], g, ox);
  }
  __syncthreads();
  red0[cg][x] = oy;
  red1[cg][x] = ox;
  __syncthreads();
  if (cg == 0) {
    float osy = red0[0][x] + red0[1][x] + red0[2][x] + red0[3][x];
    float osx = red1[0][x] + red1[1][x] + red1[2][x] + red1[3][x];
    osy = tanhf(osy) * (K_OFR / (HH - 1));
    osx = tanhf(osx) * (K_OFR / (WW - 1));
    float ry = (y + 0.5f) * (2.f / 63.f) - 1.f;
    float rx = (x + 0.5f) * (2.f / 63.f) - 1.f;
    float gx = (osx + rx + 1.f) * 0.5f * (WW - 1);
    float gy = (osy + ry + 1.f) * 0.5f * (HH - 1);
    int n = y * WW + x;
    gxy[(b * HWP + n) * 2 + 0] = gx;
    gxy[(b * HWP + n) * 2 + 1] = gy;
  }
}

// ---------------------------------------------------------------------------
// Kernel 3: bilinear sample kv at (gx,gy) -> xs -> k = wk@xs+bk, v = wv@xs+bv.
// Writes bf16 K [B][N][C] and bf16 V [B][C][N] for MFMA fragments.
// Grid 256 blocks; block = 64 points x 4 o-groups of 16.
// ---------------------------------------------------------------------------
__global__ __launch_bounds__(256) void k_sample_kv(
    const float* __restrict__ kv, const float* __restrict__ gxy,
    const float* __restrict__ wk, const float* __restrict__ bk,
    const float* __restrict__ wv, const float* __restrict__ bv,
    unsigned short* __restrict__ kb, unsigned short* __restrict__ vb) {
  __shared__ float wk_s[64 * 64];
  __shared__ float wv_s[64 * 64];
  __shared__ float xs_s[64 * 64];   // [c][n]
  int tid = threadIdx.x;
  int blk = blockIdx.x;             // b*64 + tile
  int b = blk >> 6; int n0 = (blk & 63) * 64;
#pragma unroll
  for (int i = 0; i < 16; ++i) {
    wk_s[i * 256 + tid] = wk[i * 256 + tid];
    wv_s[i * 256 + tid] = wv[i * 256 + tid];
  }
  int n = tid & 63, og = tid >> 6;
  int p = b * HWP + n0 + n;
  float gx = gxy[p * 2 + 0], gy = gxy[p * 2 + 1];
  float x0f = floorf(gx), y0f = floorf(gy);
  float wx = gx - x0f, wy = gy - y0f;
  int x0 = (int)x0f, y0 = (int)y0f;
  int x1 = x0 + 1, y1 = y0 + 1;
  float m00 = (x0 >= 0 && x0 < WW && y0 >= 0 && y0 < HH) ? 1.f : 0.f;
  float m01 = (x1 >= 0 && x1 < WW && y0 >= 0 && y0 < HH) ? 1.f : 0.f;
  float m10 = (x0 >= 0 && x0 < WW && y1 >= 0 && y1 < HH) ? 1.f : 0.f;
  float m11 = (x1 >= 0 && x1 < WW && y1 >= 0 && y1 < HH) ? 1.f : 0.f;
  int x0c = min(max(x0, 0), WW - 1), x1c = min(max(x1, 0), WW - 1);
  int y0c = min(max(y0, 0), HH - 1), y1c = min(max(y1, 0), HH - 1);
  int i00 = y0c * WW + x0c, i01 = y0c * WW + x1c;
  int i10 = y1c * WW + x0c, i11 = y1c * WW + x1c;
  float w00 = m00 * (1.f - wx) * (1.f - wy);
  float w01 = m01 * wx * (1.f - wy);
  float w10 = m10 * (1.f - wx) * wy;
  float w11 = m11 * wx * wy;

  const float* base = kv + (size_t)b * CC * HWP;
#pragma unroll 4
  for (int i = 0; i < 16; ++i) {
    int c = og * 16 + i;
    const float* pc = base + (size_t)c * HWP;
    xs_s[c * 64 + n] = w00 * pc[i00] + w01 * pc[i01] + w10 * pc[i10] + w11 * pc[i11];
  }
  __syncthreads();
  float ak[16], av[16];
#pragma unroll
  for (int oo = 0; oo < 16; ++oo) { ak[oo] = bk[og * 16 + oo]; av[oo] = bv[og * 16 + oo]; }
  for (int cg = 0; cg < 16; ++cg) {
    float p0 = xs_s[(cg * 4 + 0) * 64 + n];
    float p1 = xs_s[(cg * 4 + 1) * 64 + n];
    float p2 = xs_s[(cg * 4 + 2) * 64 + n];
    float p3 = xs_s[(cg * 4 + 3) * 64 + n];
#pragma unroll
    for (int oo = 0; oo < 16; ++oo) {
      int o = og * 16 + oo;
      const float4 k4 = *(const float4*)&wk_s[o * 64 + cg * 4];
      const float4 v4 = *(const float4*)&wv_s[o * 64 + cg * 4];
      ak[oo] = fmaf(k4.x, p0, fmaf(k4.y, p1, fmaf(k4.z, p2, fmaf(k4.w, p3, ak[oo]))));
      av[oo] = fmaf(v4.x, p0, fmaf(v4.y, p1, fmaf(v4.z, p2, fmaf(v4.w, p3, av[oo]))));
    }
  }
  // K: [b][n][c] row write, 16 contiguous bf16 = 2x uint4
  unsigned short tk[16];
#pragma unroll
  for (int oo = 0; oo < 16; ++oo) tk[oo] = f2bf(ak[oo]);
  size_t krow = (size_t)(b * NPTS + n0 + n) * CC + og * 16;
  *(uint4*)&kb[krow]     = *(const uint4*)&tk[0];
  *(uint4*)&kb[krow + 8] = *(const uint4*)&tk[8];
  // V: [b][c][n] coalesced 2B column writes
#pragma unroll
  for (int oo = 0; oo < 16; ++oo) {
    int o = og * 16 + oo;
    vb[(size_t)(b * CC + o) * NPTS + n0 + n] = f2bf(av[oo]);
  }
}

// ---------------------------------------------------------------------------
// Kernel 4: bf16 MFMA flash attention partials.
// Grid = B * NSPLIT * 64 = 512 blocks, 256 thr = 4 waves.
// Wave w: 16 queries (m = w*16..+15), full 64-key tiles.
// GEMM1: S[m][n] = Q[m][c]*K[n][c]^T   (A=q_s[m][c], B=k_s[n][c])
// GEMM2: O^T[c][m] = V[c][n]*P[m][n]^T (A=v_s[c][n], B=p_s[m][n])
// All fragment reads are n/c-contiguous ds_read_b128 from +8-padded rows.
// ---------------------------------------------------------------------------
__global__ __launch_bounds__(256) void k_attn(
    const unsigned short* __restrict__ qb, const unsigned short* __restrict__ kb,
    const unsigned short* __restrict__ vb, float* __restrict__ opart,
    float* __restrict__ dpart) {
  __shared__ short q_s[64 * LDP];
  __shared__ short k_s[64 * LDP];
  __shared__ short v_s[64 * LDP];
  __shared__ short p_s[64 * LDP];

  int tid = threadIdx.x;
  int w = tid >> 6, lane = tid & 63, quad = lane >> 4, l16 = lane & 15;
  int blk = blockIdx.x;
  int mt = blk & 63; int bns = blk >> 6; int ns = bns & 1; int b = bns >> 1;
  int m0 = mt * 64;

  const unsigned short* qbb = qb + (size_t)b * HWP * CC;
  const unsigned short* kbb = kb + (size_t)b * NPTS * CC;
  const unsigned short* vbb = vb + (size_t)b * CC * NPTS;

  // stage Q tile [m][c] (8 KB, 2 passes of 256 x 16B)
#pragma unroll
  for (int pass = 0; pass < 2; ++pass) {
    int idx = pass * 256 + tid;
    int row = idx >> 3, part = idx & 7;
    uint4 d = *(const uint4*)(qbb + (size_t)(m0 + row) * CC + part * 8);
    *(uint4*)&q_s[row * LDP + part * 8] = d;
  }

  f32x4 o_acc[4];
  float d_acc[4];
#pragma unroll
  for (int i = 0; i < 4; ++i) {
    d_acc[i] = 0.f;
    o_acc[i][0] = 0.f; o_acc[i][1] = 0.f; o_acc[i][2] = 0.f; o_acc[i][3] = 0.f;
  }

  int nbase = ns * (NPTS / NSPLIT);
  for (int it = 0; it < (NPTS / NSPLIT) / 64; ++it) {
    int n0 = nbase + it * 64;
    __syncthreads();   // protect k_s/v_s (and initial q_s) from overwrite-while-read
#pragma unroll
    for (int pass = 0; pass < 2; ++pass) {
      int idx = pass * 256 + tid;
      int row = idx >> 3, part = idx & 7;
      uint4 dk = *(const uint4*)(kbb + (size_t)(n0 + row) * CC + part * 8);
      uint4 dv = *(const uint4*)(vbb + (size_t)row * NPTS + n0 + part * 8);
      *(uint4*)&k_s[row * LDP + part * 8] = dk;
      *(uint4*)&v_s[row * LDP + part * 8] = dv;
    }
    __syncthreads();

    // GEMM1: per-wave 16m x 64n
    f32x4 s_acc[4];
#pragma unroll
    for (int t = 0; t < 4; ++t) {
      s_acc[t][0] = 0.f; s_acc[t][1] = 0.f; s_acc[t][2] = 0.f; s_acc[t][3] = 0.f;
    }
#pragma unroll
    for (int kc = 0; kc < 2; ++kc) {
      frag8 a = *(const frag8*)&q_s[(w * 16 + l16) * LDP + kc * 32 + quad * 8];
#pragma unroll
      for (int t = 0; t < 4; ++t) {
        frag8 bf = *(const frag8*)&k_s[(t * 16 + l16) * LDP + kc * 32 + quad * 8];
        s_acc[t] = __builtin_amdgcn_mfma_f32_16x16x32_bf16(a, bf, s_acc[t], 0, 0, 0);
      }
    }
    // exp (logits tiny: no max subtraction) -> P to LDS (wave-private rows)
#pragma unroll
    for (int t = 0; t < 4; ++t) {
#pragma unroll
      for (int r = 0; r < 4; ++r) {
        float pv = __expf(s_acc[t][r] * K_SCALE);
        unsigned short ph = f2bf(pv);
        p_s[(w * 16 + quad * 4 + r) * LDP + t * 16 + l16] = (short)ph;
        // denominator from the rounded value (consistent with GEMM2's P)
        d_acc[r] += __builtin_bit_cast(float, (unsigned int)ph << 16);
      }
    }
    // GEMM2: O^T[c][m] += V[c][n] * P^T[n][m]
#pragma unroll
    for (int kc = 0; kc < 2; ++kc) {
      frag8 bp = *(const frag8*)&p_s[(w * 16 + l16) * LDP + kc * 32 + quad * 8];
#pragma unroll
      for (int ct = 0; ct < 4; ++ct) {
        frag8 av = *(const frag8*)&v_s[(ct * 16 + l16) * LDP + kc * 32 + quad * 8];
        o_acc[ct] = __builtin_amdgcn_mfma_f32_16x16x32_bf16(av, bp, o_acc[ct], 0, 0, 0);
      }
    }
  }

  // O^T lane layout: c = ct*16 + quad*4 + reg, m = w*16 + l16
  float* op = opart + (size_t)(ns * BB + b) * HWP * CC + (size_t)(m0 + w * 16 + l16) * CC;
#pragma unroll
  for (int ct = 0; ct < 4; ++ct) {
    float4 o4;
    o4.x = o_acc[ct][0]; o4.y = o_acc[ct][1]; o4.z = o_acc[ct][2]; o4.w = o_acc[ct][3];
    *(float4*)&op[ct * 16 + quad * 4] = o4;
  }
  // denominator: reduce across the 16 n-columns (lane bits 0..3)
#pragma unroll
  for (int r = 0; r < 4; ++r) {
    float d = d_acc[r];
    d += __shfl_xor(d, 1); d += __shfl_xor(d, 2);
    d += __shfl_xor(d, 4); d += __shfl_xor(d, 8);
    if (l16 == 0)
      dpart[(ns * BB + b) * HWP + m0 + w * 16 + quad * 4 + r] = d;
  }
}

// ---------------------------------------------------------------------------
// Kernel 5: combine partials, normalize, project with wo, write d_out.
// Grid = B * 64 m-tiles = 256 blocks.
// ---------------------------------------------------------------------------
__global__ __launch_bounds__(256) void k_out(
    const float* __restrict__ opart, const float* __restrict__ dpart,
    const float* __restrict__ wo, const float* __restrict__ bo,
    float* __restrict__ out) {
  __shared__ float wo_s[CC * CC];
  __shared__ float t_s[64 * 65];    // [m][c] padded
  int tid = threadIdx.x;
  int blk = blockIdx.x;             // b*64 + mt
  int b = blk >> 6, mt = blk & 63, m0 = mt * 64;
  for (int i = tid; i < CC * CC; i += 256) wo_s[i] = wo[i];

  const float* o0 = opart + (size_t)(0 * BB + b) * HWP * CC;
  const float* o1 = opart + (size_t)(1 * BB + b) * HWP * CC;
  const float* d0 = dpart + (0 * BB + b) * HWP;
  const float* d1 = dpart + (1 * BB + b) * HWP;
#pragma unroll
  for (int it = 0; it < 16; ++it) {
    int idx = it * 256 + tid;
    int m = idx >> 6, c = idx & 63;
    float denom = d0[m0 + m] + d1[m0 + m];
    float val = (o0[(size_t)(m0 + m) * CC + c] + o1[(size_t)(m0 + m) * CC + c]) / denom;
    t_s[m * 65 + c] = val;
  }
  __syncthreads();
  int ml = tid & 63, og = tid >> 6;
  for (int oo = 0; oo < 16; ++oo) {
    int o = og * 16 + oo;
    float acc = bo[o];
#pragma unroll
    for (int c = 0; c < 64; ++c) acc = fmaf(wo_s[o * CC + c], t_s[ml * 65 + c], acc);
    out[(size_t)(b * CC + o) * HWP + m0 + ml] = acc;
  }
}

// ---------------------------------------------------------------------------
extern "C" void kernel_launch(void* const* d_in, const int* in_sizes, int n_in,
                              void* d_out, int out_size, void* d_ws, size_t ws_size,
                              hipStream_t stream) {
  const float* prompt = (const float*)d_in[0];
  const float* kv     = (const float*)d_in[1];
  const float* wq     = (const float*)d_in[2];
  const float* bq     = (const float*)d_in[3];
  const float* wk     = (const float*)d_in[4];
  const float* bk     = (const float*)d_in[5];
  const float* wv     = (const float*)d_in[6];
  const float* bv     = (const float*)d_in[7];
  const float* wo     = (const float*)d_in[8];
  const float* bo     = (const float*)d_in[9];
  const float* dw_w   = (const float*)d_in[10];
  const float* dw_b   = (const float*)d_in[11];
  const float* ln_w   = (const float*)d_in[12];
  const float* ln_b   = (const float*)d_in[13];
  const float* off_w  = (const float*)d_in[14];
  float* out = (float*)d_out;
  float* ws  = (float*)d_ws;

  float* qf             = ws + QF_OFF;
  unsigned short* qb    = (unsigned short*)(ws + QB_OFF);
  float* gxy            = ws + GXY_OFF;
  unsigned short* kb    = (unsigned short*)(ws + KB_OFF);
  unsigned short* vb    = (unsigned short*)(ws + VB_OFF);
  float* opart          = ws + OP_OFF;
  float* dpart          = ws + DP_OFF;

  hipLaunchKernelGGL(k_qproj, dim3(BB * 64), dim3(256), 0, stream,
                     prompt, wq, bq, qf, qb);
  hipLaunchKernelGGL(k_offsets, dim3(BB * HH), dim3(256), 0, stream,
                     qf, dw_w, dw_b, ln_w, ln_b, off_w, gxy);
  hipLaunchKernelGGL(k_sample_kv, dim3(BB * 64), dim3(256), 0, stream,
                     kv, gxy, wk, bk, wv, bv, kb, vb);
  hipLaunchKernelGGL(k_attn, dim3(BB * NSPLIT * 64), dim3(256), 0, stream,
                     qb, kb, vb, opart, dpart);
  hipLaunchKernelGGL(k_out, dim3(BB * 64), dim3(256), 0, stream,
                     opart, dpart, wo, bo, out);
}